// Round 1
// baseline (353.373 us; speedup 1.0000x reference)
//
#include <hip/hip_runtime.h>
#include <hip/hip_bf16.h>

// Global max pool over spatial dims: X[16,256,128,128] f32 -> out[16,256,1,1].
// Each (b,c) slice = 128*128 = 16384 contiguous floats. One block per slice.
// 4096 blocks x 256 threads; each thread: 16 coalesced float4 loads + fmax,
// then wave64 shuffle reduce + LDS cross-wave reduce.

__global__ __launch_bounds__(256)
void spatial_pool2d_34565896798756_kernel(const float* __restrict__ X,
                                          float* __restrict__ out) {
    const int bc  = blockIdx.x;          // 0..4095
    const int tid = threadIdx.x;         // 0..255

    // Slice base: 16384 floats = 4096 float4s. 256 threads -> 16 float4 each.
    const float4* __restrict__ p =
        reinterpret_cast<const float4*>(X + (size_t)bc * 16384);

    float m = -INFINITY;
#pragma unroll
    for (int i = 0; i < 16; ++i) {
        float4 v = p[tid + i * 256];     // stride-256 float4: coalesced per iter
        m = fmaxf(m, fmaxf(fmaxf(v.x, v.y), fmaxf(v.z, v.w)));
    }

    // Wave64 reduction (6 butterfly steps).
#pragma unroll
    for (int off = 32; off > 0; off >>= 1)
        m = fmaxf(m, __shfl_down(m, off, 64));

    // Cross-wave reduction via LDS (4 waves/block).
    __shared__ float smem[4];
    const int wave = tid >> 6;
    if ((tid & 63) == 0) smem[wave] = m;
    __syncthreads();

    if (tid == 0) {
        out[bc] = fmaxf(fmaxf(smem[0], smem[1]), fmaxf(smem[2], smem[3]));
    }
}

extern "C" void kernel_launch(void* const* d_in, const int* in_sizes, int n_in,
                              void* d_out, int out_size, void* d_ws, size_t ws_size,
                              hipStream_t stream) {
    const float* X  = (const float*)d_in[0];
    float* out      = (float*)d_out;
    // out_size == 16*256 == 4096 slices
    spatial_pool2d_34565896798756_kernel<<<out_size, 256, 0, stream>>>(X, out);
}

// Round 2
// 351.852 us; speedup vs baseline: 1.0043x; 1.0043x over previous
//
#include <hip/hip_runtime.h>
#include <hip/hip_bf16.h>

// Global max pool over spatial dims: X[16,256,128,128] f32 -> out[16,256,1,1].
// Each (b,c) slice = 16384 contiguous floats. One block per slice.
// 4096 blocks x 256 threads; each thread: 16 coalesced float4 loads into
// 4 INDEPENDENT accumulators (breaks the dependent fmax chain, keeps all
// 16 loads in flight), then wave64 shuffle reduce + LDS cross-wave reduce.

__global__ __launch_bounds__(256)
void spatial_pool2d_34565896798756_kernel(const float* __restrict__ X,
                                          float* __restrict__ out) {
    const int bc  = blockIdx.x;          // 0..4095
    const int tid = threadIdx.x;         // 0..255

    const float4* __restrict__ p =
        reinterpret_cast<const float4*>(X + (size_t)bc * 16384);

    // 4 independent accumulator chains -> ILP; loads all independent.
    float m0 = -INFINITY, m1 = -INFINITY, m2 = -INFINITY, m3 = -INFINITY;
#pragma unroll
    for (int i = 0; i < 4; ++i) {
        float4 a = p[tid + (4 * i + 0) * 256];
        float4 b = p[tid + (4 * i + 1) * 256];
        float4 c = p[tid + (4 * i + 2) * 256];
        float4 d = p[tid + (4 * i + 3) * 256];
        m0 = fmaxf(m0, fmaxf(fmaxf(a.x, a.y), fmaxf(a.z, a.w)));
        m1 = fmaxf(m1, fmaxf(fmaxf(b.x, b.y), fmaxf(b.z, b.w)));
        m2 = fmaxf(m2, fmaxf(fmaxf(c.x, c.y), fmaxf(c.z, c.w)));
        m3 = fmaxf(m3, fmaxf(fmaxf(d.x, d.y), fmaxf(d.z, d.w)));
    }
    float m = fmaxf(fmaxf(m0, m1), fmaxf(m2, m3));

    // Wave64 reduction (6 butterfly steps).
#pragma unroll
    for (int off = 32; off > 0; off >>= 1)
        m = fmaxf(m, __shfl_down(m, off, 64));

    // Cross-wave reduction via LDS (4 waves/block).
    __shared__ float smem[4];
    const int wave = tid >> 6;
    if ((tid & 63) == 0) smem[wave] = m;
    __syncthreads();

    if (tid == 0) {
        out[bc] = fmaxf(fmaxf(smem[0], smem[1]), fmaxf(smem[2], smem[3]));
    }
}

extern "C" void kernel_launch(void* const* d_in, const int* in_sizes, int n_in,
                              void* d_out, int out_size, void* d_ws, size_t ws_size,
                              hipStream_t stream) {
    const float* X  = (const float*)d_in[0];
    float* out      = (float*)d_out;
    // out_size == 16*256 == 4096 slices
    spatial_pool2d_34565896798756_kernel<<<out_size, 256, 0, stream>>>(X, out);
}